// Round 12
// baseline (479.823 us; speedup 1.0000x reference)
//
#include <hip/hip_runtime.h>

#define HSZ  32
#define TLEN 1024

typedef _Float16 half8 __attribute__((ext_vector_type(8)));
typedef float    f32x4 __attribute__((ext_vector_type(4)));

__device__ __forceinline__ float rcp_f(float x){ return __builtin_amdgcn_rcpf(x); }
__device__ __forceinline__ float exp2_f(float x){ return __builtin_amdgcn_exp2f(x); }
#define SCL_S (-1.442695040888963f)   // sigmoid arg prescale: -log2(e)
#define SCL_T ( 2.885390081777927f)   // tanh arg prescale: +2*log2(e)

__device__ __forceinline__ f32x4 mfma16(half8 a, half8 b, f32x4 c){
  return __builtin_amdgcn_mfma_f32_16x16x32_f16(a, b, c, 0, 0, 0);
}
// LDS-only barrier: drain lgkmcnt without draining vmcnt (x prefetch in flight).
__device__ __forceinline__ void lds_barrier(){
  asm volatile("s_waitcnt lgkmcnt(0)\n\ts_barrier" ::: "memory");
}
__device__ __forceinline__ unsigned int packh2(float a, float b){
  _Float16 ha = (_Float16)a, hb = (_Float16)b;
  return (unsigned int)__builtin_bit_cast(unsigned short, ha)
       | ((unsigned int)__builtin_bit_cast(unsigned short, hb) << 16);
}

// gate quad from prescaled args; paired rcps; updates CV in place.
#define ACT4(A0,A1,A2,A3, CV, IV, FV, GV, OV)                  \
  { float Zi_ = exp2_f(A0), Zf_ = exp2_f(A1);                  \
    float Zg_ = exp2_f(A2), Zo_ = exp2_f(A3);                  \
    float di_ = 1.f+Zi_, df_ = 1.f+Zf_;                        \
    float dg_ = 1.f+Zg_, dq_ = 1.f+Zo_;                        \
    float r1_ = rcp_f(di_*df_); IV = r1_*df_; FV = r1_*di_;    \
    float r2_ = rcp_f(dg_*dq_);                                \
    GV = fmaf(-2.f, r2_*dq_, 1.f); OV = r2_*dg_;               \
    CV = fmaf(FV, CV, IV*GV); }

// paired tanh(c) for two states: one rcp.
#define TANHPAIR(CA, CB, OA, OB, HA, HB)                       \
  { float ZA_ = exp2_f(SCL_T*(CA)), ZB_ = exp2_f(SCL_T*(CB));  \
    float dA_ = 1.f+ZA_, dB_ = 1.f+ZB_;                        \
    float re_ = rcp_f(dA_*dB_);                                \
    float qA_ = re_*dB_*(OA), qB_ = re_*dA_*(OB);              \
    HA = fmaf(-2.f, qA_, OA); HB = fmaf(-2.f, qB_, OB); }

// 4 WAVES / 16-BATCH TILE (1 wave/SIMD). SLOT-ALIGNED PERMUTATION:
// tile tau's A tile-row r loads physical gate row 32*(r&3)+8*(r>>2)+tau, so
// lane (g,c) D-regs j=0..3 are gates (i,f,g,o) of state 8g+tau -- the
// activated h lands in B-FRAGMENT SLOT tau of lane (g,c) itself. Wave w owns
// tiles {2w,2w+1} of BOTH layers (12 MFMA, 4 ACT4 -- perfectly balanced);
// its 2 h-slots per layer are in-register; the other 6 come via ONE packed
// ds_write_b32 + ONE ds_read_b128 per layer. Exchange cost per block-step
// drops from 24xb128+16 writes to 8xb128-reads + 8xb32-writes.
// Skewed schedule (L1(t) + L0(t+1) per iter), one lgkm-only barrier/step,
// parity double buffer; h f16-hi only; weights hi+lo split (R8-validated).
__global__ __launch_bounds__(256, 1) void lstm2_slot(
    const float* __restrict__ x,
    const float* __restrict__ Wih0, const float* __restrict__ Whh0,
    const float* __restrict__ bih0, const float* __restrict__ bhh0,
    const float* __restrict__ Wih1, const float* __restrict__ Whh1,
    const float* __restrict__ bih1, const float* __restrict__ bhh1,
    const float* __restrict__ Wfc,  const float* __restrict__ bfc,
    float* __restrict__ out, int Tn)
{
  // [parity][layer][(g*16+c)*8 + slot] f16
  __shared__ __align__(16) _Float16 hx[2][2][1024];

  const int tid = threadIdx.x;
  const int w   = tid >> 6;          // wave 0..3: owns tiles 2w, 2w+1
  const int l   = tid & 63;
  const int c   = l & 15;            // batch col == A tile-row index
  const int g   = l >> 4;            // k-group == D row-group
  const int ta  = 2*w, tb = 2*w + 1;
  const int b0  = blockIdx.x * 16;
  const int Pc  = 32*(c & 3) + 8*(c >> 2);          // permuted A-row base
  const float sA = ((c & 3) == 2) ? SCL_T : SCL_S;  // A-row gate type
  const float scj[4] = {SCL_S, SCL_S, SCL_T, SCL_S};
  const f32x4 zero4 = {0.f, 0.f, 0.f, 0.f};
  const int rdI = (g*16 + c)*8;      // b128 read base (16B aligned)
  const int wrI = rdI + ta;          // u32 write (even half-index -> 4B aligned)

  for (int i = tid; i < 2*2*1024; i += 256) (&hx[0][0][0])[i] = (_Float16)0.0f;

  // ---- weights: tiles ta,tb; hi+lo split; prescaled ----
  half8 W0h[2], W0l[2], WHh[2], WHl[2], WIh[2], WIl[2];
  #pragma unroll
  for (int tt = 0; tt < 2; ++tt){
    const int pr = Pc + ta + tt;
    const float* p0 = Whh0 + pr*HSZ + 8*g;
    const float* p1 = Whh1 + pr*HSZ + 8*g;
    const float* p2 = Wih1 + pr*HSZ + 8*g;
    #pragma unroll
    for (int j = 0; j < 8; ++j){
      float v0 = p0[j]*sA, v1 = p1[j]*sA, v2 = p2[j]*sA;
      _Float16 a = (_Float16)v0; W0h[tt][j] = a; W0l[tt][j] = (_Float16)(v0 - (float)a);
      _Float16 b = (_Float16)v1; WHh[tt][j] = b; WHl[tt][j] = (_Float16)(v1 - (float)b);
      _Float16 d = (_Float16)v2; WIh[tt][j] = d; WIl[tt][j] = (_Float16)(v2 - (float)d);
    }
  }
  // D-side per-state constants: gate row 32j + 8g + tau
  float wx[2][4], bs0[2][4];
  f32x4 bias1[2];
  #pragma unroll
  for (int tt = 0; tt < 2; ++tt){
    #pragma unroll
    for (int j = 0; j < 4; ++j){
      int r = 32*j + 8*g + ta + tt;
      wx[tt][j]   = Wih0[r] * scj[j];
      bs0[tt][j]  = (bih0[r] + bhh0[r]) * scj[j];
      bias1[tt][j] = (bih1[r] + bhh1[r]) * scj[j];
    }
  }

  const float* xp = x + (size_t)(b0 + c) * Tn;
  float c0a = 0.f, c0b = 0.f, c1a = 0.f, c1b = 0.f;
  float h1a = 0.f, h1b = 0.f;

  __syncthreads();   // zero-init visible

  // ---- prologue: L0(0), no MFMA (h0(-1)=0); h1(-1)=0 from init ----
  {
    float x0 = xp[0];
    float iva,fva,gva,ova, ivb,fvb,gvb,ovb, h0a, h0b;
    ACT4(fmaf(x0,wx[0][0],bs0[0][0]), fmaf(x0,wx[0][1],bs0[0][1]),
         fmaf(x0,wx[0][2],bs0[0][2]), fmaf(x0,wx[0][3],bs0[0][3]),
         c0a, iva,fva,gva,ova);
    ACT4(fmaf(x0,wx[1][0],bs0[1][0]), fmaf(x0,wx[1][1],bs0[1][1]),
         fmaf(x0,wx[1][2],bs0[1][2]), fmaf(x0,wx[1][3],bs0[1][3]),
         c0b, ivb,fvb,gvb,ovb);
    TANHPAIR(c0a, c0b, ova, ovb, h0a, h0b);
    *(unsigned int*)&hx[0][0][wrI] = packh2(h0a, h0b);
  }
  __syncthreads();
  half8 Bh0 = *(const half8*)&hx[0][0][rdI];   // h0(0)
  half8 Bh1 = *(const half8*)&hx[0][1][rdI];   // h1(-1) = 0
  float xv = xp[1];

  // iter t: L1(t) -> h1(t) AND L0(t+1) -> h0(t+1); write parity Q=(t+1)&1
#define STEP(Q, XNI)                                                       \
  {                                                                        \
    float xn = xp[(XNI)];                                                  \
    f32x4 e0, e1;                                                          \
    e0[0]=fmaf(xv,wx[0][0],bs0[0][0]); e0[1]=fmaf(xv,wx[0][1],bs0[0][1]);  \
    e0[2]=fmaf(xv,wx[0][2],bs0[0][2]); e0[3]=fmaf(xv,wx[0][3],bs0[0][3]);  \
    e1[0]=fmaf(xv,wx[1][0],bs0[1][0]); e1[1]=fmaf(xv,wx[1][1],bs0[1][1]);  \
    e1[2]=fmaf(xv,wx[1][2],bs0[1][2]); e1[3]=fmaf(xv,wx[1][3],bs0[1][3]);  \
    f32x4 u0 = mfma16(WHh[0], Bh1, bias1[0]);                              \
    f32x4 u1 = mfma16(WHh[1], Bh1, bias1[1]);                              \
    f32x4 v0 = mfma16(WIh[0], Bh0, zero4);                                 \
    f32x4 v1 = mfma16(WIh[1], Bh0, zero4);                                 \
    e0 = mfma16(W0h[0], Bh0, e0);  e1 = mfma16(W0h[1], Bh0, e1);           \
    u0 = mfma16(WHl[0], Bh1, u0);  u1 = mfma16(WHl[1], Bh1, u1);           \
    v0 = mfma16(WIl[0], Bh0, v0);  v1 = mfma16(WIl[1], Bh0, v1);           \
    e0 = mfma16(W0l[0], Bh0, e0);  e1 = mfma16(W0l[1], Bh0, e1);           \
    f32x4 a0 = u0 + v0, a1 = u1 + v1;                                      \
    /* L1(t) */                                                            \
    float i1a,f1a,g1a,o1a, i1b,f1b,g1b,o1b;                                \
    ACT4(a0[0],a0[1],a0[2],a0[3], c1a, i1a,f1a,g1a,o1a);                   \
    ACT4(a1[0],a1[1],a1[2],a1[3], c1b, i1b,f1b,g1b,o1b);                   \
    TANHPAIR(c1a, c1b, o1a, o1b, h1a, h1b);                                \
    *(unsigned int*)&hx[(Q)][1][wrI] = packh2(h1a, h1b);                   \
    /* L0(t+1) */                                                          \
    float i0a,f0a,g0a,o0a, i0b,f0b,g0b,o0b, h0a, h0b;                      \
    ACT4(e0[0],e0[1],e0[2],e0[3], c0a, i0a,f0a,g0a,o0a);                   \
    ACT4(e1[0],e1[1],e1[2],e1[3], c0b, i0b,f0b,g0b,o0b);                   \
    TANHPAIR(c0a, c0b, o0a, o0b, h0a, h0b);                                \
    *(unsigned int*)&hx[(Q)][0][wrI] = packh2(h0a, h0b);                   \
    lds_barrier();                                                         \
    Bh0 = *(const half8*)&hx[(Q)][0][rdI];                                 \
    Bh1 = *(const half8*)&hx[(Q)][1][rdI];                                 \
    xv = xn;                                                               \
  }

  for (int T0 = 0; T0 < Tn; T0 += 2){
    STEP(1, (T0+2 < Tn) ? T0+2 : Tn-1);
    STEP(0, (T0+3 < Tn) ? T0+3 : Tn-1);
  }
#undef STEP

  // ---- FC head: out[b0+c] = dot(h1_final[:,c], Wfc) + bfc ----
  __syncthreads();
  float* sc = (float*)&hx[0][0][0];
  sc[(8*g + ta)*17 + c] = h1a;
  sc[(8*g + tb)*17 + c] = h1b;
  __syncthreads();
  if (tid < 16){
    float acc = bfc[0];
    #pragma unroll 8
    for (int k = 0; k < HSZ; ++k) acc = fmaf(sc[k*17 + tid], Wfc[k], acc);
    out[b0 + tid] = acc;
  }
}

extern "C" void kernel_launch(void* const* d_in, const int* in_sizes, int n_in,
                              void* d_out, int out_size, void* d_ws, size_t ws_size,
                              hipStream_t stream) {
  const float* x    = (const float*)d_in[0];
  const float* Wih0 = (const float*)d_in[1];
  const float* Whh0 = (const float*)d_in[2];
  const float* bih0 = (const float*)d_in[3];
  const float* bhh0 = (const float*)d_in[4];
  const float* Wih1 = (const float*)d_in[5];
  const float* Whh1 = (const float*)d_in[6];
  const float* bih1 = (const float*)d_in[7];
  const float* bhh1 = (const float*)d_in[8];
  const float* Wfc  = (const float*)d_in[9];
  const float* bfc  = (const float*)d_in[10];
  float* out = (float*)d_out;

  const int Tn = TLEN;
  const int B  = in_sizes[0] / Tn;     // x is (B, T, 1)

  dim3 block(256);
  dim3 grid(B / 16);                   // one 16-batch tile per block, 4 waves
  hipLaunchKernelGGL(lstm2_slot, grid, block, 0, stream,
                     x, Wih0, Whh0, bih0, bhh0, Wih1, Whh1, bih1, bhh1,
                     Wfc, bfc, out, Tn);
}